// Round 13
// baseline (408.460 us; speedup 1.0000x reference)
//
#include <hip/hip_runtime.h>
#include <stdint.h>

#define N_H    128
#define N_INV  96
#define EPSF   134      // f32 epilogue quarter stride
#define HPS    36       // H piece stride (32+4) bf16 -> same bank math as proven HS=132
#define NWAVE  16
#define CHUNK  256      // 16 waves x 16 edges
#define NBLK   256      // persistent blocks; LDS pins exactly 1 per CU
#define KS1    10
#define KS2    4
#define W1_BYTES 81920
#define W2_BYTES 32768
#define W_BYTES  (W1_BYTES + W2_BYTES)        // 114688
#define WBUF     2176   // max(H piece 16*36*2=1152, epi quarter 4*134*4=2144)
#define BIAS_OFF (W_BYTES + NWAVE * WBUF)     // 149504
#define SMEM_BYTES (BIAS_OFF + 2048)          // 151552

typedef __bf16 bf16x8 __attribute__((ext_vector_type(8)));
typedef __bf16 bf16x4 __attribute__((ext_vector_type(4)));
typedef float  f32x4  __attribute__((ext_vector_type(4)));

__device__ __forceinline__ unsigned short f2bf(float f) {
    union { float f; unsigned u; } v; v.f = f;
    unsigned u = v.u;
    u += 0x7FFFu + ((u >> 16) & 1u);   // RNE
    return (unsigned short)(u >> 16);
}

// Pack weights in MFMA-fragment order, W1 then W2 contiguous:
//   wpk[(ks*8+nt)*512 + lane*8 + j] = W[k=ks*32+(lane>>4)*8+j][n=nt*16+(lane&15)]
__global__ void prep_weights(const float* __restrict__ W1,
                             const float* __restrict__ W2,
                             unsigned short* __restrict__ w1p,
                             unsigned short* __restrict__ w2p) {
    int idx = blockIdx.x * blockDim.x + threadIdx.x;
    if (idx < KS1 * 8 * 64 * 8) {
        int j = idx & 7, lane = (idx >> 3) & 63, nt = (idx >> 9) & 7, ks = idx >> 12;
        int k = ks * 32 + (lane >> 4) * 8 + j;
        int n = nt * 16 + (lane & 15);
        w1p[idx] = f2bf(W1[(size_t)k * N_H + n]);
    } else {
        int r = idx - KS1 * 8 * 64 * 8;
        if (r < KS2 * 8 * 64 * 8) {
            int j = r & 7, lane = (r >> 3) & 63, nt = (r >> 9) & 7, ks = r >> 12;
            int k = ks * 32 + (lane >> 4) * 8 + j;
            int n = nt * 16 + (lane & 15);
            w2p[r] = f2bf(W2[(size_t)k * N_H + n]);
        }
    }
}

// node_invariant -> bf16 so each gather fragment is a single 16B load.
__global__ void prep_ninv(const float* __restrict__ ninv,
                          unsigned short* __restrict__ nb, int n4) {
    int i = blockIdx.x * blockDim.x + threadIdx.x;
    if (i < n4) {
        float4 v = ((const float4*)ninv)[i];
        ((ushort4*)nb)[i] = make_ushort4(f2bf(v.x), f2bf(v.y), f2bf(v.z), f2bf(v.w));
    }
}

// Persistent, 16 waves/block (4 waves/SIMD -- 2x the latency hiding of R10's
// 8-wave config at identical 151.5KB LDS). Each wave owns 16 edges/chunk.
// GEMM2 consumes H in 16x32 pieces staged through a 2176B/wave buffer;
// epilogue runs in 4-row quarters through the same buffer.
__global__ __launch_bounds__(1024, 4)
void edge_mlp(const unsigned short* __restrict__ ninvb, const float* __restrict__ ef,
              const int* __restrict__ ei,
              const unsigned short* __restrict__ wpk,
              const float* __restrict__ b1g, const float* __restrict__ b2g,
              const float* __restrict__ gg, const float* __restrict__ btg,
              float* __restrict__ out, int E, int cbase, int crem) {
    extern __shared__ __align__(16) char smem[];

    const int tid  = threadIdx.x;
    const int wv   = tid >> 6;
    const int lane = tid & 63;
    const int lr   = lane & 15;
    const int lkg  = lane >> 4;
    const int lk   = lkg * 8;
    const int qr   = lkg * 4;

    const int b     = blockIdx.x;
    const int c0    = b * cbase + (b < crem ? b : crem);
    const int cnt   = cbase + (b < crem ? 1 : 0);
    if (cnt <= 0) return;
    const int clast = c0 + cnt - 1;

    // ---- stage 112KB weights (7 x 1KB per wave) + 2KB bias/ln params ----
    {
        const char* gsrc = (const char*)wpk;
        #pragma unroll
        for (int i = 0; i < 7; ++i) {
            int ch = wv * 7 + i;
            __builtin_amdgcn_global_load_lds(
                (const __attribute__((address_space(1))) void*)(gsrc + ch * 1024 + lane * 16),
                (__attribute__((address_space(3))) void*)(smem + ch * 1024),
                16, 0, 0);
        }
        if (wv == 0) {
            const float* srcs[4] = { b1g, b2g, gg, btg };
            #pragma unroll
            for (int a = 0; a < 4; ++a) {
                #pragma unroll
                for (int h = 0; h < 2; ++h) {
                    __builtin_amdgcn_global_load_lds(
                        (const __attribute__((address_space(1))) void*)(srcs[a] + h * 64 + lane),
                        (__attribute__((address_space(3))) void*)(smem + BIAS_OFF + a * 512 + h * 256),
                        4, 0, 0);
                }
            }
        }
    }

    const float* b1l = (const float*)(smem + BIAS_OFF);
    const float* b2l = (const float*)(smem + BIAS_OFF + 512);
    const float* gl  = (const float*)(smem + BIAS_OFF + 1024);
    const float* btl = (const float*)(smem + BIAS_OFF + 1536);

    // ---- per-wave prologue: chunk c0 gathers/ef; ei for c0+1, c0+2 ----
    bf16x8 an[6];
    f32x4  efa[4][2];
    int sA, dA, eS, eD;
    {
        int er = c0 * CHUNK + wv * 16 + lr;
        int ee = er < E ? er : E - 1;
        int s0 = ei[ee], d0 = ei[(size_t)E + ee];
        #pragma unroll
        for (int q = 0; q < 6; ++q) {
            int row = q < 3 ? s0 : d0;
            an[q] = *(const bf16x8*)(ninvb + (size_t)row * N_INV + (q % 3) * 32 + lk);
        }
        const float* ap = ef + (size_t)ee * N_H;
        #pragma unroll
        for (int j = 0; j < 4; ++j) {
            efa[j][0] = *(const f32x4*)(ap + j * 32 + lk);
            efa[j][1] = *(const f32x4*)(ap + j * 32 + lk + 4);
        }
        int c1 = c0 + 1 <= clast ? c0 + 1 : clast;
        int e1 = c1 * CHUNK + wv * 16 + lr; e1 = e1 < E ? e1 : E - 1;
        sA = ei[e1]; dA = ei[(size_t)E + e1];
        int c2 = c0 + 2 <= clast ? c0 + 2 : clast;
        int e2 = c2 * CHUNK + wv * 16 + lr; e2 = e2 < E ? e2 : E - 1;
        eS = ei[e2]; eD = ei[(size_t)E + e2];
    }

    __syncthreads();   // the only block-wide barrier

    char* buf = smem + W_BYTES + wv * WBUF;
    __bf16* hp = (__bf16*)buf;     // H piece [16][36]
    float*  ep = (float*)buf;      // epi quarter [4][134]

    for (int c = c0; c <= clast; ++c) {
        const int eb = c * CHUNK + wv * 16;

        // ---- convert ef fragments to bf16 (frees the f32 regs) ----
        bf16x8 anef[4];
        #pragma unroll
        for (int j = 0; j < 4; ++j) {
            union { __bf16 e[8]; bf16x8 v; } ua;
            #pragma unroll
            for (int m = 0; m < 4; ++m) {
                ua.e[m]     = (__bf16)efa[j][0][m];
                ua.e[4 + m] = (__bf16)efa[j][1][m];
            }
            anef[j] = ua.v;
        }

        // ---- GEMM1: [16x320]x[320x128], B from LDS ----
        f32x4 acc[8] = {};
        #pragma unroll
        for (int ks = 0; ks < KS1; ++ks) {
            bf16x8 bfr[8];
            #pragma unroll
            for (int nt = 0; nt < 8; ++nt)
                bfr[nt] = *(const bf16x8*)(smem + ((ks * 8 + nt) << 10) + (lane << 4));
            bf16x8 a = (ks < 6) ? an[ks] : anef[ks - 6];
            __builtin_amdgcn_s_setprio(1);
            #pragma unroll
            for (int nt = 0; nt < 8; ++nt)
                acc[nt] = __builtin_amdgcn_mfma_f32_16x16x32_bf16(a, bfr[nt], acc[nt], 0, 0, 0);
            __builtin_amdgcn_s_setprio(0);
        }

        // ---- gathers(c+1) now (an dead); rotate ei pipeline ----
        #pragma unroll
        for (int q = 0; q < 6; ++q) {
            int row = q < 3 ? sA : dA;
            an[q] = *(const bf16x8*)(ninvb + (size_t)row * N_INV + (q % 3) * 32 + lk);
        }
        sA = eS; dA = eD;
        {
            int c3 = c + 3 <= clast ? c + 3 : clast;
            int e3 = c3 * CHUNK + wv * 16 + lr; e3 = e3 < E ? e3 : E - 1;
            eS = ei[e3]; eD = ei[(size_t)E + e3];
        }

        // ---- residual quarters 0,1 issued; GEMM2 covers them ----
        f32x4 res[4][2];
        #pragma unroll
        for (int q = 0; q < 2; ++q) {
            #pragma unroll
            for (int it = 0; it < 2; ++it) {
                int row4 = (it << 1) + (lane >> 5);
                int c4   = (lane & 31) << 2;
                int erow = eb + 4 * q + row4;
                int ec   = erow < E ? erow : E - 1;
                res[q][it] = *(const f32x4*)(ef + (size_t)ec * N_H + c4);
            }
        }

        // ---- GEMM2 piecewise: stage H cols [32ks,32ks+32), consume, repeat ----
        f32x4 acc2[8] = {};
        #pragma unroll
        for (int ks = 0; ks < KS2; ++ks) {
            #pragma unroll
            for (int p = 0; p < 2; ++p) {
                int nt = 2 * ks + p;
                float bb = b1l[nt * 16 + lr];
                #pragma unroll
                for (int i = 0; i < 4; ++i) {
                    float v = acc[nt][i] + bb;
                    v = v > 0.0f ? v : 0.0f;
                    hp[(qr + i) * HPS + p * 16 + lr] = (__bf16)v;
                }
            }
            __builtin_amdgcn_wave_barrier();
            union { bf16x4 h[2]; bf16x8 v; } ua;
            ua.h[0] = *(const bf16x4*)(hp + lr * HPS + lk);
            ua.h[1] = *(const bf16x4*)(hp + lr * HPS + lk + 4);
            __builtin_amdgcn_s_setprio(1);
            #pragma unroll
            for (int nt = 0; nt < 8; ++nt) {
                bf16x8 w = *(const bf16x8*)(smem + W1_BYTES + ((ks * 8 + nt) << 10) + (lane << 4));
                acc2[nt] = __builtin_amdgcn_mfma_f32_16x16x32_bf16(ua.v, w, acc2[nt], 0, 0, 0);
            }
            __builtin_amdgcn_s_setprio(0);
            __builtin_amdgcn_wave_barrier();
        }

        // ---- residual quarters 2,3 ----
        #pragma unroll
        for (int q = 2; q < 4; ++q) {
            #pragma unroll
            for (int it = 0; it < 2; ++it) {
                int row4 = (it << 1) + (lane >> 5);
                int c4   = (lane & 31) << 2;
                int erow = eb + 4 * q + row4;
                int ec   = erow < E ? erow : E - 1;
                res[q][it] = *(const f32x4*)(ef + (size_t)ec * N_H + c4);
            }
        }

        // ---- bias + LayerNorm (vals kept in acc2) ----
        float s1[4] = {0.f, 0.f, 0.f, 0.f};
        float s2[4] = {0.f, 0.f, 0.f, 0.f};
        #pragma unroll
        for (int nt = 0; nt < 8; ++nt) {
            float bb = b2l[nt * 16 + lr];
            #pragma unroll
            for (int i = 0; i < 4; ++i) {
                float v = acc2[nt][i] + bb;
                acc2[nt][i] = v;
                s1[i] += v;
                s2[i] += v * v;
            }
        }
        #pragma unroll
        for (int m = 1; m < 16; m <<= 1) {
            #pragma unroll
            for (int i = 0; i < 4; ++i) {
                s1[i] += __shfl_xor(s1[i], m);
                s2[i] += __shfl_xor(s2[i], m);
            }
        }
        float mu[4], rs[4];
        #pragma unroll
        for (int i = 0; i < 4; ++i) {
            mu[i] = s1[i] * (1.0f / 128.0f);
            float var = s2[i] * (1.0f / 128.0f) - mu[i] * mu[i];
            rs[i] = rsqrtf(var + 1e-5f);
        }

        // ---- epilogue: 4 quarters of 4 rows through the f32 LDS buffer ----
        #pragma unroll
        for (int q = 0; q < 4; ++q) {
            if (lkg == q) {
                #pragma unroll
                for (int nt = 0; nt < 8; ++nt) {
                    int cc = nt * 16 + lr;
                    float g  = gl[cc];
                    float bt = btl[cc];
                    #pragma unroll
                    for (int i = 0; i < 4; ++i)
                        ep[i * EPSF + cc] = (acc2[nt][i] - mu[i]) * rs[i] * g + bt;
                }
            }
            __builtin_amdgcn_wave_barrier();
            #pragma unroll
            for (int it = 0; it < 2; ++it) {
                int row4 = (it << 1) + (lane >> 5);
                int c4   = (lane & 31) << 2;
                int erow = eb + 4 * q + row4;
                if (erow < E) {
                    f32x4 nv = *(const f32x4*)(ep + row4 * EPSF + c4);
                    *(f32x4*)(out + (size_t)erow * N_H + c4) = nv + res[q][it];
                }
            }
            __builtin_amdgcn_wave_barrier();
        }

        // ---- issue ef fragments (c+1); GEMM1(c+1) ks0-5 covers the latency ----
        {
            int cn = c + 1 <= clast ? c + 1 : clast;
            int en = cn * CHUNK + wv * 16 + lr; en = en < E ? en : E - 1;
            const float* ap = ef + (size_t)en * N_H;
            #pragma unroll
            for (int j = 0; j < 4; ++j) {
                efa[j][0] = *(const f32x4*)(ap + j * 32 + lk);
                efa[j][1] = *(const f32x4*)(ap + j * 32 + lk + 4);
            }
        }
    }
}

extern "C" void kernel_launch(void* const* d_in, const int* in_sizes, int n_in,
                              void* d_out, int out_size, void* d_ws, size_t ws_size,
                              hipStream_t stream) {
    const float* ninv = (const float*)d_in[0];
    const float* ef   = (const float*)d_in[1];
    const int*   ei   = (const int*)d_in[2];
    const float* W1   = (const float*)d_in[3];
    const float* b1   = (const float*)d_in[4];
    const float* W2   = (const float*)d_in[5];
    const float* b2   = (const float*)d_in[6];
    const float* g    = (const float*)d_in[7];
    const float* bt   = (const float*)d_in[8];
    float* out = (float*)d_out;

    const int E = in_sizes[1] / N_H;
    const int NNODE = in_sizes[0] / N_INV;

    unsigned short* w1p = (unsigned short*)d_ws;             // 40960 bf16
    unsigned short* w2p = w1p + KS1 * 8 * 64 * 8;            // 16384 bf16 (contiguous)
    unsigned short* nb  = w2p + KS2 * 8 * 64 * 8;            // NNODE*96 bf16

    hipFuncSetAttribute((const void*)edge_mlp,
                        hipFuncAttributeMaxDynamicSharedMemorySize, SMEM_BYTES);

    int prep_total = (KS1 + KS2) * 8 * 64 * 8;
    prep_weights<<<(prep_total + 255) / 256, 256, 0, stream>>>(W1, W2, w1p, w2p);

    int n4 = NNODE * N_INV / 4;
    prep_ninv<<<(n4 + 255) / 256, 256, 0, stream>>>(ninv, nb, n4);

    int nchunks = (E + CHUNK - 1) / CHUNK;
    int cbase = nchunks / NBLK;
    int crem  = nchunks - cbase * NBLK;
    edge_mlp<<<NBLK, 1024, SMEM_BYTES, stream>>>(nb, ef, ei, w1p, b1, b2, g, bt,
                                                 out, E, cbase, crem);
}

// Round 14
// 311.702 us; speedup vs baseline: 1.3104x; 1.3104x over previous
//
#include <hip/hip_runtime.h>
#include <stdint.h>

#define N_H    128
#define N_INV  96
#define EPSF   134      // f32 epilogue quarter stride
#define HPS    36       // H piece stride (32+4) bf16
#define NWAVE  12
#define CHUNK  192      // 12 waves x 16 edges
#define NBLK   256      // persistent blocks; LDS pins exactly 1 per CU
#define KS1    10
#define KS2    4
#define W1_BYTES 81920
#define W2_BYTES 32768
#define W_BYTES  (W1_BYTES + W2_BYTES)        // 114688
#define WBUF     2176   // max(H piece 16*36*2=1152, epi quarter 4*134*4=2144)
#define BIAS_OFF (W_BYTES + NWAVE * WBUF)     // 140800
#define SMEM_BYTES (BIAS_OFF + 2048)          // 142848

typedef __bf16 bf16x8 __attribute__((ext_vector_type(8)));
typedef __bf16 bf16x4 __attribute__((ext_vector_type(4)));
typedef float  f32x4  __attribute__((ext_vector_type(4)));

__device__ __forceinline__ unsigned short f2bf(float f) {
    union { float f; unsigned u; } v; v.f = f;
    unsigned u = v.u;
    u += 0x7FFFu + ((u >> 16) & 1u);   // RNE
    return (unsigned short)(u >> 16);
}

// Pack weights in MFMA-fragment order, W1 then W2 contiguous:
//   wpk[(ks*8+nt)*512 + lane*8 + j] = W[k=ks*32+(lane>>4)*8+j][n=nt*16+(lane&15)]
__global__ void prep_weights(const float* __restrict__ W1,
                             const float* __restrict__ W2,
                             unsigned short* __restrict__ w1p,
                             unsigned short* __restrict__ w2p) {
    int idx = blockIdx.x * blockDim.x + threadIdx.x;
    if (idx < KS1 * 8 * 64 * 8) {
        int j = idx & 7, lane = (idx >> 3) & 63, nt = (idx >> 9) & 7, ks = idx >> 12;
        int k = ks * 32 + (lane >> 4) * 8 + j;
        int n = nt * 16 + (lane & 15);
        w1p[idx] = f2bf(W1[(size_t)k * N_H + n]);
    } else {
        int r = idx - KS1 * 8 * 64 * 8;
        if (r < KS2 * 8 * 64 * 8) {
            int j = r & 7, lane = (r >> 3) & 63, nt = (r >> 9) & 7, ks = r >> 12;
            int k = ks * 32 + (lane >> 4) * 8 + j;
            int n = nt * 16 + (lane & 15);
            w2p[r] = f2bf(W2[(size_t)k * N_H + n]);
        }
    }
}

// node_invariant -> bf16 so each gather fragment is a single 16B load.
__global__ void prep_ninv(const float* __restrict__ ninv,
                          unsigned short* __restrict__ nb, int n4) {
    int i = blockIdx.x * blockDim.x + threadIdx.x;
    if (i < n4) {
        float4 v = ((const float4*)ninv)[i];
        ((ushort4*)nb)[i] = make_ushort4(f2bf(v.x), f2bf(v.y), f2bf(v.z), f2bf(v.w));
    }
}

// Persistent, 12 waves/block = 3 waves/SIMD (1.5x R10's hiding; fits the
// 170-reg budget unlike R13's 4/SIMD which spilled). TILES=1, piecewise-H
// GEMM2, residual recovered from the bf16 ef fragments (anef) via LDS RMW
// in the epilogue -- no residual global loads, no held f32 ef registers.
__global__ __launch_bounds__(768, 3)
void edge_mlp(const unsigned short* __restrict__ ninvb, const float* __restrict__ ef,
              const int* __restrict__ ei,
              const unsigned short* __restrict__ wpk,
              const float* __restrict__ b1g, const float* __restrict__ b2g,
              const float* __restrict__ gg, const float* __restrict__ btg,
              float* __restrict__ out, int E, int cbase, int crem) {
    extern __shared__ __align__(16) char smem[];

    const int tid  = threadIdx.x;
    const int wv   = tid >> 6;
    const int lane = tid & 63;
    const int lr   = lane & 15;
    const int lkg  = lane >> 4;
    const int lk   = lkg * 8;
    const int qr   = lkg * 4;

    const int b     = blockIdx.x;
    const int c0    = b * cbase + (b < crem ? b : crem);
    const int cnt   = cbase + (b < crem ? 1 : 0);
    if (cnt <= 0) return;
    const int clast = c0 + cnt - 1;

    // ---- stage 112KB weights (112 x 1KB chunks over 12 waves) + 2KB params ----
    {
        const char* gsrc = (const char*)wpk;
        #pragma unroll
        for (int i = 0; i < 10; ++i) {
            int ch = i * 12 + wv;
            if (ch < 112) {
                __builtin_amdgcn_global_load_lds(
                    (const __attribute__((address_space(1))) void*)(gsrc + ch * 1024 + lane * 16),
                    (__attribute__((address_space(3))) void*)(smem + ch * 1024),
                    16, 0, 0);
            }
        }
        if (wv == 0) {
            const float* srcs[4] = { b1g, b2g, gg, btg };
            #pragma unroll
            for (int a = 0; a < 4; ++a) {
                #pragma unroll
                for (int h = 0; h < 2; ++h) {
                    __builtin_amdgcn_global_load_lds(
                        (const __attribute__((address_space(1))) void*)(srcs[a] + h * 64 + lane),
                        (__attribute__((address_space(3))) void*)(smem + BIAS_OFF + a * 512 + h * 256),
                        4, 0, 0);
                }
            }
        }
    }

    const float* b1l = (const float*)(smem + BIAS_OFF);
    const float* b2l = (const float*)(smem + BIAS_OFF + 512);
    const float* gl  = (const float*)(smem + BIAS_OFF + 1024);
    const float* btl = (const float*)(smem + BIAS_OFF + 1536);

    // ---- per-wave prologue: chunk c0 gathers/ef; ei for c0+1, c0+2 ----
    bf16x8 an[6];
    f32x4  efa[4][2];
    int sA, dA, eS, eD;
    {
        int er = c0 * CHUNK + wv * 16 + lr;
        int ee = er < E ? er : E - 1;
        int s0 = ei[ee], d0 = ei[(size_t)E + ee];
        #pragma unroll
        for (int q = 0; q < 6; ++q) {
            int row = q < 3 ? s0 : d0;
            an[q] = *(const bf16x8*)(ninvb + (size_t)row * N_INV + (q % 3) * 32 + lk);
        }
        const float* ap = ef + (size_t)ee * N_H;
        #pragma unroll
        for (int j = 0; j < 4; ++j) {
            efa[j][0] = *(const f32x4*)(ap + j * 32 + lk);
            efa[j][1] = *(const f32x4*)(ap + j * 32 + lk + 4);
        }
        int c1 = c0 + 1 <= clast ? c0 + 1 : clast;
        int e1 = c1 * CHUNK + wv * 16 + lr; e1 = e1 < E ? e1 : E - 1;
        sA = ei[e1]; dA = ei[(size_t)E + e1];
        int c2 = c0 + 2 <= clast ? c0 + 2 : clast;
        int e2 = c2 * CHUNK + wv * 16 + lr; e2 = e2 < E ? e2 : E - 1;
        eS = ei[e2]; eD = ei[(size_t)E + e2];
    }

    __syncthreads();   // the only block-wide barrier

    char* buf = smem + W_BYTES + wv * WBUF;
    __bf16* hp = (__bf16*)buf;     // H piece [16][36]
    float*  ep = (float*)buf;      // epi quarter [4][134]

    for (int c = c0; c <= clast; ++c) {
        const int eb = c * CHUNK + wv * 16;

        // ---- ef f32 -> bf16 fragments; efa dies here (regs freed) ----
        bf16x8 anef[4];
        #pragma unroll
        for (int j = 0; j < 4; ++j) {
            union { __bf16 e[8]; bf16x8 v; } ua;
            #pragma unroll
            for (int m = 0; m < 4; ++m) {
                ua.e[m]     = (__bf16)efa[j][0][m];
                ua.e[4 + m] = (__bf16)efa[j][1][m];
            }
            anef[j] = ua.v;
        }

        // ---- GEMM1: [16x320]x[320x128], B from LDS ----
        f32x4 acc[8] = {};
        #pragma unroll
        for (int ks = 0; ks < KS1; ++ks) {
            bf16x8 bfr[8];
            #pragma unroll
            for (int nt = 0; nt < 8; ++nt)
                bfr[nt] = *(const bf16x8*)(smem + ((ks * 8 + nt) << 10) + (lane << 4));
            bf16x8 a = (ks < 6) ? an[ks] : anef[ks - 6];
            __builtin_amdgcn_s_setprio(1);
            #pragma unroll
            for (int nt = 0; nt < 8; ++nt)
                acc[nt] = __builtin_amdgcn_mfma_f32_16x16x32_bf16(a, bfr[nt], acc[nt], 0, 0, 0);
            __builtin_amdgcn_s_setprio(0);
        }

        // ---- gathers(c+1) now (an dead); rotate ei pipeline ----
        #pragma unroll
        for (int q = 0; q < 6; ++q) {
            int row = q < 3 ? sA : dA;
            an[q] = *(const bf16x8*)(ninvb + (size_t)row * N_INV + (q % 3) * 32 + lk);
        }
        sA = eS; dA = eD;
        {
            int c3 = c + 3 <= clast ? c + 3 : clast;
            int e3 = c3 * CHUNK + wv * 16 + lr; e3 = e3 < E ? e3 : E - 1;
            eS = ei[e3]; eD = ei[(size_t)E + e3];
        }

        // ---- GEMM2 piecewise: stage H cols [32ks,32ks+32), consume, repeat ----
        f32x4 acc2[8] = {};
        #pragma unroll
        for (int ks = 0; ks < KS2; ++ks) {
            #pragma unroll
            for (int p = 0; p < 2; ++p) {
                int nt = 2 * ks + p;
                float bb = b1l[nt * 16 + lr];
                #pragma unroll
                for (int i = 0; i < 4; ++i) {
                    float v = acc[nt][i] + bb;
                    v = v > 0.0f ? v : 0.0f;
                    hp[(qr + i) * HPS + p * 16 + lr] = (__bf16)v;
                }
            }
            __builtin_amdgcn_wave_barrier();
            union { bf16x4 h[2]; bf16x8 v; } ua;
            ua.h[0] = *(const bf16x4*)(hp + lr * HPS + lk);
            ua.h[1] = *(const bf16x4*)(hp + lr * HPS + lk + 4);
            __builtin_amdgcn_s_setprio(1);
            #pragma unroll
            for (int nt = 0; nt < 8; ++nt) {
                bf16x8 w = *(const bf16x8*)(smem + W1_BYTES + ((ks * 8 + nt) << 10) + (lane << 4));
                acc2[nt] = __builtin_amdgcn_mfma_f32_16x16x32_bf16(ua.v, w, acc2[nt], 0, 0, 0);
            }
            __builtin_amdgcn_s_setprio(0);
            __builtin_amdgcn_wave_barrier();
        }

        // ---- bias + LayerNorm (vals kept in acc2) ----
        float s1[4] = {0.f, 0.f, 0.f, 0.f};
        float s2[4] = {0.f, 0.f, 0.f, 0.f};
        #pragma unroll
        for (int nt = 0; nt < 8; ++nt) {
            float bb = b2l[nt * 16 + lr];
            #pragma unroll
            for (int i = 0; i < 4; ++i) {
                float v = acc2[nt][i] + bb;
                acc2[nt][i] = v;
                s1[i] += v;
                s2[i] += v * v;
            }
        }
        #pragma unroll
        for (int m = 1; m < 16; m <<= 1) {
            #pragma unroll
            for (int i = 0; i < 4; ++i) {
                s1[i] += __shfl_xor(s1[i], m);
                s2[i] += __shfl_xor(s2[i], m);
            }
        }
        float mu[4], rs[4];
        #pragma unroll
        for (int i = 0; i < 4; ++i) {
            mu[i] = s1[i] * (1.0f / 128.0f);
            float var = s2[i] * (1.0f / 128.0f) - mu[i] * mu[i];
            rs[i] = rsqrtf(var + 1e-5f);
        }

        // ---- epilogue: 4 quarters; residual added in-LDS from anef ----
        #pragma unroll
        for (int q = 0; q < 4; ++q) {
            if (lkg == q) {                 // norm writer: rows 4q..4q+3
                #pragma unroll
                for (int nt = 0; nt < 8; ++nt) {
                    int cc = nt * 16 + lr;
                    float g  = gl[cc];
                    float bt = btl[cc];
                    #pragma unroll
                    for (int i = 0; i < 4; ++i)
                        ep[i * EPSF + cc] = (acc2[nt][i] - mu[i]) * rs[i] * g + bt;
                }
            }
            __builtin_amdgcn_wave_barrier();
            if ((lr >> 2) == q) {           // residual RMW: this lane's ef row
                #pragma unroll
                for (int j = 0; j < 4; ++j) {
                    float* p = ep + (lr & 3) * EPSF + j * 32 + lkg * 8;
                    f32x4 v0 = *(const f32x4*)p;
                    f32x4 v1 = *(const f32x4*)(p + 4);
                    #pragma unroll
                    for (int m = 0; m < 4; ++m) {
                        v0[m] += (float)anef[j][m];
                        v1[m] += (float)anef[j][4 + m];
                    }
                    *(f32x4*)p = v0;
                    *(f32x4*)(p + 4) = v1;
                }
            }
            __builtin_amdgcn_wave_barrier();
            #pragma unroll
            for (int it = 0; it < 2; ++it) {   // coalesced store
                int row4 = (it << 1) + (lane >> 5);
                int c4   = (lane & 31) << 2;
                int erow = eb + 4 * q + row4;
                if (erow < E) {
                    f32x4 nv = *(const f32x4*)(ep + row4 * EPSF + c4);
                    *(f32x4*)(out + (size_t)erow * N_H + c4) = nv;
                }
            }
            __builtin_amdgcn_wave_barrier();
        }

        // ---- issue ef fragments (c+1); GEMM1(c+1) ks0-5 covers the latency ----
        {
            int cn = c + 1 <= clast ? c + 1 : clast;
            int en = cn * CHUNK + wv * 16 + lr; en = en < E ? en : E - 1;
            const float* ap = ef + (size_t)en * N_H;
            #pragma unroll
            for (int j = 0; j < 4; ++j) {
                efa[j][0] = *(const f32x4*)(ap + j * 32 + lk);
                efa[j][1] = *(const f32x4*)(ap + j * 32 + lk + 4);
            }
        }
    }
}

extern "C" void kernel_launch(void* const* d_in, const int* in_sizes, int n_in,
                              void* d_out, int out_size, void* d_ws, size_t ws_size,
                              hipStream_t stream) {
    const float* ninv = (const float*)d_in[0];
    const float* ef   = (const float*)d_in[1];
    const int*   ei   = (const int*)d_in[2];
    const float* W1   = (const float*)d_in[3];
    const float* b1   = (const float*)d_in[4];
    const float* W2   = (const float*)d_in[5];
    const float* b2   = (const float*)d_in[6];
    const float* g    = (const float*)d_in[7];
    const float* bt   = (const float*)d_in[8];
    float* out = (float*)d_out;

    const int E = in_sizes[1] / N_H;
    const int NNODE = in_sizes[0] / N_INV;

    unsigned short* w1p = (unsigned short*)d_ws;             // 40960 bf16
    unsigned short* w2p = w1p + KS1 * 8 * 64 * 8;            // 16384 bf16 (contiguous)
    unsigned short* nb  = w2p + KS2 * 8 * 64 * 8;            // NNODE*96 bf16

    hipFuncSetAttribute((const void*)edge_mlp,
                        hipFuncAttributeMaxDynamicSharedMemorySize, SMEM_BYTES);

    int prep_total = (KS1 + KS2) * 8 * 64 * 8;
    prep_weights<<<(prep_total + 255) / 256, 256, 0, stream>>>(W1, W2, w1p, w2p);

    int n4 = NNODE * N_INV / 4;
    prep_ninv<<<(n4 + 255) / 256, 256, 0, stream>>>(ninv, nb, n4);

    int nchunks = (E + CHUNK - 1) / CHUNK;
    int cbase = nchunks / NBLK;
    int crem  = nchunks - cbase * NBLK;
    edge_mlp<<<NBLK, 768, SMEM_BYTES, stream>>>(nb, ef, ei, w1p, b1, b2, g, bt,
                                                out, E, cbase, crem);
}